// Round 6
// baseline (89.376 us; speedup 1.0000x reference)
//
#include <hip/hip_runtime.h>
#include <hip/hip_fp16.h>

// Radon3D loss on MI355X — project the DIFFERENCE volume (radon is linear).
// Geometry (D=H=W=64, 120 angles over [0,120] deg): L=91, pad top=left=13.
//   ix(i,j) = 45*c*linj + 32 + 45*s - s*i,  iy(i,j) = 45*s*linj + 32 - 45*c + c*i
//   (unit steps in i: the 0.5*(L-1) unnormalization cancels the linspace step)
// TWO 4-byte canvases (P0: half2 diffs slices s0,s0+1; P1: s0+2,s0+3), ODD
// word stride 69 -> conflict-free for any line direction.
// i-range SPLIT across 2 blocks (partial column sums are linear in i):
// halves write f32 float4 partials to d_ws; finalize does |p0+p1| + reduce.
// Coords shifted +1 (nonneg) and clamped to [0,65]: out-of-support samples
// hit the zero border with zero weight == map_coordinates cval=0.
#define DD 64
#define NA 120
#define NS 64
#define LL 91
#define PS 67
#define PSTR 69               // ODD word stride -> no structured bank conflicts
#define NCELL (PS * PSTR)     // 4623 words = 18.5 KB per canvas
#define NSL 4                 // slices per block (2 per canvas)
#define NANG 4                // angles per block
#define JT 96                 // j-lanes per angle (91 active)
#define NTHR (NANG * JT)      // 384 threads = 6 waves
#define NSP (NS / NSL)        // 16 slice groups
#define NAP (NA / NANG)       // 30 angle groups
#define NBLK_HALF (NSP * NAP) // 480
#define NBLKS (2 * NBLK_HALF) // 960
#define IH_SPLIT 46           // half 0: i in [0,46), half 1: i in [46,91)
#define PHALF (NSP * NA * JT) // float4 entries per half = 184320 (2.95 MB)

static __device__ __forceinline__ __half2 u2h(unsigned int u) {
    union { unsigned int u; __half2 h; } v; v.u = u; return v.h;
}
static __device__ __forceinline__ unsigned int h2u(__half2 h) {
    union { __half2 h; unsigned int u; } v; v.h = h; return v.u;
}

__global__ __launch_bounds__(NTHR, 6) void radon_half_kernel(
    const float* __restrict__ vout, const float* __restrict__ vgt,
    float4* __restrict__ part)
{
    __shared__ unsigned int P0[NCELL];   // slices s0, s0+1
    __shared__ unsigned int P1[NCELL];   // slices s0+2, s0+3

    const int bid = blockIdx.x;
    const int h   = bid / NBLK_HALF;            // i-half 0/1
    const int rem = bid - h * NBLK_HALF;
    const int sp  = rem / NAP;                  // slice group 0..15
    const int ap  = rem - sp * NAP;             // angle group 0..29
    const int s0  = sp * NSL;
    const int t   = threadIdx.x;

    // 1) zero both padded canvases
    for (int idx = t; idx < NCELL; idx += NTHR) {
        P0[idx] = 0u;
        P1[idx] = 0u;
    }
    __syncthreads();

    // 2) stage fp16 diffs of 4 slices: im_s[d][w] = vol[0,0,d,s,w]
    for (int idx = t; idx < DD * DD; idx += NTHR) {
        const int d = idx >> 6, w = idx & 63;
        const int g = d * 4096 + s0 * 64 + w;
        const float d0 = vout[g]       - vgt[g];
        const float d1 = vout[g + 64]  - vgt[g + 64];
        const float d2 = vout[g + 128] - vgt[g + 128];
        const float d3 = vout[g + 192] - vgt[g + 192];
        const int ci = (d + 1) * PSTR + (w + 1);
        P0[ci] = h2u(__floats2half2_rn(d0, d1));
        P1[ci] = h2u(__floats2half2_rn(d2, d3));
    }
    __syncthreads();

    // 3) projection over this block's i-half; thread = (angle slot, column j)
    const int ja = t / JT;
    const int j  = t - ja * JT;
    const int a  = ap * NANG + ja;
    const float theta = (float)a * (float)(3.14159265358979323846 * 120.0 / 119.0 / 180.0);
    const float c = cosf(theta), sn = sinf(theta);

    if (j < LL) {
        const float linj = fmaf((float)j, 2.0f / 90.0f, -1.0f);
        // +1 shift: coords in [0,65] after clamp; canvas row/col 0 is border
        const float bx1 = fmaf(c,  linj, 1.0f) * 45.0f - 12.0f + 45.0f * sn;
        const float by1 = fmaf(sn, linj, 1.0f) * 45.0f - 12.0f - 45.0f * c;
        const int i0 = h ? IH_SPLIT : 0;
        const int i1 = h ? LL : IH_SPLIT;
        __half2 acc0 = __floats2half2_rn(0.f, 0.f);
        __half2 acc1 = acc0;
        for (int i = i0; i < i1; ++i) {
            // independent per-iteration coords -> deep pipelining
            const float xs = fminf(fmaxf(fmaf(-(float)i, sn, bx1), 0.0f), 65.0f);
            const float ys = fminf(fmaxf(fmaf( (float)i, c,  by1), 0.0f), 65.0f);
            const int ix = (int)xs;            // trunc == floor (nonneg)
            const int iy = (int)ys;
            const float wx = xs - (float)ix;
            const float wy = ys - (float)iy;
            const __half2 wx2 = __float2half2_rn(wx);
            const __half2 wy2 = __float2half2_rn(wy);
            const int ci = iy * PSTR + ix;
            const unsigned int a00 = P0[ci],        a01 = P0[ci + 1];
            const unsigned int a10 = P0[ci + PSTR], a11 = P0[ci + PSTR + 1];
            const unsigned int b00 = P1[ci],        b01 = P1[ci + 1];
            const unsigned int b10 = P1[ci + PSTR], b11 = P1[ci + PSTR + 1];
            const __half2 t0  = __hfma2(wx2, __hsub2(u2h(a01), u2h(a00)), u2h(a00));
            const __half2 bb0 = __hfma2(wx2, __hsub2(u2h(a11), u2h(a10)), u2h(a10));
            acc0 = __hadd2(acc0, __hfma2(wy2, __hsub2(bb0, t0), t0));
            const __half2 t1  = __hfma2(wx2, __hsub2(u2h(b01), u2h(b00)), u2h(b00));
            const __half2 bb1 = __hfma2(wx2, __hsub2(u2h(b11), u2h(b10)), u2h(b10));
            acc1 = __hadd2(acc1, __hfma2(wy2, __hsub2(bb1, t1), t1));
        }
        const float2 a0f = __half22float2(acc0);
        const float2 a1f = __half22float2(acc1);
        part[h * PHALF + (sp * NA + a) * JT + j] =
            make_float4(a0f.x, a0f.y, a1f.x, a1f.y);
    }
}

#define NENT (NSP * NA * LL)   // 174720 finalize entries

__global__ __launch_bounds__(256) void finalize_kernel(
    const float4* __restrict__ part, float* __restrict__ out)
{
    __shared__ float wsum[4];
    float v = 0.f;
    for (int e = blockIdx.x * 256 + threadIdx.x; e < NENT; e += gridDim.x * 256) {
        const int spa = e / LL;               // sp*NA + a
        const int j   = e - spa * LL;
        const int pi  = spa * JT + j;
        const float4 p0 = part[pi];
        const float4 p1 = part[PHALF + pi];
        v += fabsf(p0.x + p1.x) + fabsf(p0.y + p1.y)
           + fabsf(p0.z + p1.z) + fabsf(p0.w + p1.w);
    }
    #pragma unroll
    for (int off = 32; off > 0; off >>= 1)
        v += __shfl_down(v, off);
    const int wave = threadIdx.x >> 6, lane = threadIdx.x & 63;
    if (lane == 0) wsum[wave] = v;
    __syncthreads();
    if (threadIdx.x == 0) {
        const float s = wsum[0] + wsum[1] + wsum[2] + wsum[3];
        atomicAdd(out, s * (1.0f / (float)(NA * LL)));
    }
}

extern "C" void kernel_launch(void* const* d_in, const int* in_sizes, int n_in,
                              void* d_out, int out_size, void* d_ws, size_t ws_size,
                              hipStream_t stream) {
    const float* vout = (const float*)d_in[0];
    const float* vgt  = (const float*)d_in[1];
    float* out = (float*)d_out;
    float4* part = (float4*)d_ws;   // 2 * 184320 float4 = 5.9 MB

    hipMemsetAsync(out, 0, sizeof(float), stream);
    radon_half_kernel<<<NBLKS, NTHR, 0, stream>>>(vout, vgt, part);
    finalize_kernel<<<240, 256, 0, stream>>>(part, out);
}

// Round 7
// 77.785 us; speedup vs baseline: 1.1490x; 1.1490x over previous
//
#include <hip/hip_runtime.h>
#include <hip/hip_fp16.h>

// Radon3D loss on MI355X — project the DIFFERENCE volume (radon is linear).
// Geometry (D=H=W=64, 120 angles over [0,120] deg): L=91, pad top=left=13.
//   ix(i,j) = 45*c*linj + 32 + 45*s - s*i,  iy(i,j) = 45*s*linj + 32 - 45*c + c*i
//   (unit steps in i: the 0.5*(L-1) unnormalization cancels the linspace step)
// WIDE 16-byte canvas cells: [D(y,x) 4-slice fp16 | D(y,x+1) 4-slice fp16]
// (x-neighbor duplicated) -> ALL 16 bilinear corner values arrive in just
// 2 x ds_read_b128 (rows y, y+1) instead of 4 x ds_read2_b32 = 8 dword
// accesses. LDS-pipe cycles per sample halve (R4-R6 evidence: kernel is
// LDS-pipe-bound, not VALU/conflict/occupancy-bound).
// Coords shifted +1 (nonneg), clamped to [0,65]: out-of-support samples hit
// the zero border with zero weight == map_coordinates mode='constant' cval=0.
#define DD 64
#define NA 120
#define NS 64
#define LL 91
#define PS 67
#define PSTR 69               // cell stride per row
#define NCELL (PS * PSTR)     // 4623 cells * 16 B = 74.0 KB
#define NSL 4                 // slices per block
#define NANG 8                // angles per block
#define JT 96                 // j-lanes per angle (91 active)
#define NTHR (NANG * JT)      // 768 threads = 12 waves
#define NSP (NS / NSL)        // 16 slice groups
#define NAP (NA / NANG)       // 15 angle groups
#define NBLKS (NSP * NAP)     // 240 blocks -> <=1 per CU, perfectly balanced

static __device__ __forceinline__ __half2 u2h(unsigned int u) {
    union { unsigned int u; __half2 h; } v; v.u = u; return v.h;
}
static __device__ __forceinline__ unsigned int h2u(__half2 h) {
    union { __half2 h; unsigned int u; } v; v.h = h; return v.u;
}

__global__ __launch_bounds__(NTHR) void radon_loss_kernel(
    const float* __restrict__ vout, const float* __restrict__ vgt,
    float* __restrict__ out)
{
    __shared__ uint4 C[NCELL];           // wide canvas, 74 KB
    __shared__ float wsum[NTHR / 64];

    const int bid = blockIdx.x;
    const int sp = bid / NAP;            // slice group 0..15
    const int ap = bid - sp * NAP;       // angle group 0..14
    const int s0 = sp * NSL;
    const int t = threadIdx.x;

    // 1) zero the padded wide canvas
    for (int idx = t; idx < NCELL; idx += NTHR)
        C[idx] = make_uint4(0u, 0u, 0u, 0u);
    __syncthreads();

    // 2) stage fp16 diffs of 4 slices. Pixel (d,w) -> 8 B pack, written to
    //    cell(d+1, w+1).lo (as "x" entry) and cell(d+1, w).hi (as "x+1" entry).
    for (int idx = t; idx < DD * DD; idx += NTHR) {
        const int d = idx >> 6, w = idx & 63;
        const int g = d * 4096 + s0 * 64 + w;
        const float d0 = vout[g]       - vgt[g];
        const float d1 = vout[g + 64]  - vgt[g + 64];
        const float d2 = vout[g + 128] - vgt[g + 128];
        const float d3 = vout[g + 192] - vgt[g + 192];
        uint2 v8;
        v8.x = h2u(__floats2half2_rn(d0, d1));
        v8.y = h2u(__floats2half2_rn(d2, d3));
        const int rb = (d + 1) * PSTR + w;
        ((uint2*)&C[rb + 1])[0] = v8;    // D(y, x=w+1), lo half
        ((uint2*)&C[rb])[1]     = v8;    // D(y, x=w)'s x+1 entry, hi half
    }
    __syncthreads();

    // 3) projection: thread = (angle slot, column j); full i-range per thread
    const int ja = t / JT;
    const int j  = t - ja * JT;
    const int a  = ap * NANG + ja;
    const float theta = (float)a * (float)(3.14159265358979323846 * 120.0 / 119.0 / 180.0);
    const float c = cosf(theta), sn = sinf(theta);

    float val = 0.f;
    if (j < LL) {
        const float linj = fmaf((float)j, 2.0f / 90.0f, -1.0f);
        // +1 shift: coords in [0,65] after clamp; canvas row/col 0 is border
        const float bx1 = fmaf(c,  linj, 1.0f) * 45.0f - 12.0f + 45.0f * sn;
        const float by1 = fmaf(sn, linj, 1.0f) * 45.0f - 12.0f - 45.0f * c;
        __half2 acc01 = __floats2half2_rn(0.f, 0.f);
        __half2 acc23 = acc01;
        for (int i = 0; i < LL; ++i) {
            // independent per-iteration coords -> pipelinable
            const float xs = fminf(fmaxf(fmaf(-(float)i, sn, bx1), 0.0f), 65.0f);
            const float ys = fminf(fmaxf(fmaf( (float)i, c,  by1), 0.0f), 65.0f);
            const int ix = (int)xs;            // trunc == floor (nonneg)
            const int iy = (int)ys;
            const float wx = xs - (float)ix;
            const float wy = ys - (float)iy;
            const __half2 wx2 = __float2half2_rn(wx);
            const __half2 wy2 = __float2half2_rn(wy);
            const int ci = iy * PSTR + ix;
            const uint4 q0 = C[ci];            // row y  : [D(x) | D(x+1)]
            const uint4 q1 = C[ci + PSTR];     // row y+1: [D(x) | D(x+1)]
            // slices 0,1
            const __half2 t01 = __hfma2(wx2, __hsub2(u2h(q0.z), u2h(q0.x)), u2h(q0.x));
            const __half2 b01 = __hfma2(wx2, __hsub2(u2h(q1.z), u2h(q1.x)), u2h(q1.x));
            acc01 = __hadd2(acc01, __hfma2(wy2, __hsub2(b01, t01), t01));
            // slices 2,3
            const __half2 t23 = __hfma2(wx2, __hsub2(u2h(q0.w), u2h(q0.y)), u2h(q0.y));
            const __half2 b23 = __hfma2(wx2, __hsub2(u2h(q1.w), u2h(q1.y)), u2h(q1.y));
            acc23 = __hadd2(acc23, __hfma2(wy2, __hsub2(b23, t23), t23));
        }
        const float2 a01 = __half22float2(acc01);
        const float2 a23 = __half22float2(acc23);
        val = fabsf(a01.x) + fabsf(a01.y) + fabsf(a23.x) + fabsf(a23.y);
    }

    // 4) block reduction + one scaled atomic per block
    #pragma unroll
    for (int off = 32; off > 0; off >>= 1)
        val += __shfl_down(val, off);
    const int wave = t >> 6, lane = t & 63;
    if (lane == 0) wsum[wave] = val;
    __syncthreads();
    if (t == 0) {
        float v = 0.f;
        #pragma unroll
        for (int wv = 0; wv < NTHR / 64; ++wv) v += wsum[wv];
        atomicAdd(out, v * (1.0f / (float)(NA * LL)));
    }
}

extern "C" void kernel_launch(void* const* d_in, const int* in_sizes, int n_in,
                              void* d_out, int out_size, void* d_ws, size_t ws_size,
                              hipStream_t stream) {
    const float* vout = (const float*)d_in[0];
    const float* vgt  = (const float*)d_in[1];
    float* out = (float*)d_out;

    hipMemsetAsync(out, 0, sizeof(float), stream);
    radon_loss_kernel<<<NBLKS, NTHR, 0, stream>>>(vout, vgt, out);
}